// Round 1
// baseline (480.057 us; speedup 1.0000x reference)
//
#include <hip/hip_runtime.h>
#include <hip/hip_bf16.h>
#include <stdint.h>

// ---------------------------------------------------------------------------
// SelfAttention: X[4,2048,256] fp32; Wq/Wk/Wv [256,2048]; Wo [2048,256]; bo[256]
// Pipeline (all bf16 MFMA 16x16x32, fp32 accum):
//   cast:  Xb = bf16(X); Wqt/Wkt = bf16(0.25*W^T); Wvt/Wot = bf16(W^T)
//   q = Xb @ Wqt^T   [8192][2048] bf16   (scale folded)
//   k = Xb @ Wkt^T   [8192][2048] bf16
//   vt = Wvt @ Xb^T  [2048][8192] bf16   (V transposed: rows = h*256+d)
//   flash attention per (b,h,64 q-rows) -> ctx [8192][2048] bf16
//   out = ctx @ Wot^T + bo  fp32
// ---------------------------------------------------------------------------

using short8 = __attribute__((ext_vector_type(8))) short;   // 8 bf16 = 4 VGPR
using f32x4  = __attribute__((ext_vector_type(4))) float;

#define MFMA16(a, b, c) __builtin_amdgcn_mfma_f32_16x16x32_bf16((a), (b), (c), 0, 0, 0)

__device__ __forceinline__ uint16_t f2bf(float f) {
  union { float f; uint32_t u; } v; v.f = f;
  uint32_t u = v.u;
  u += 0x7fffu + ((u >> 16) & 1u);     // round-to-nearest-even
  return (uint16_t)(u >> 16);
}

// global -> LDS direct (16B per lane; LDS dest = wave-uniform base + lane*16)
__device__ __forceinline__ void gll16(const void* g, void* l) {
  __builtin_amdgcn_global_load_lds(
      (const __attribute__((address_space(1))) void*)g,
      (__attribute__((address_space(3))) void*)l, 16, 0, 0);
}

// ---------------------------------------------------------------------------
// cast X fp32 -> bf16 (vectorized)
__global__ __launch_bounds__(256) void cast_x_k(const float* __restrict__ X,
                                                uint16_t* __restrict__ Xb, int n4) {
  int i = blockIdx.x * 256 + threadIdx.x;
  if (i >= n4) return;
  float4 v = ((const float4*)X)[i];
  union { uint16_t u[4]; uint2 p; } r;
  r.u[0] = f2bf(v.x); r.u[1] = f2bf(v.y); r.u[2] = f2bf(v.z); r.u[3] = f2bf(v.w);
  ((uint2*)Xb)[i] = r.p;
}

// transpose-cast: W[R][C] fp32 -> Wt[C][R] bf16, times scale. grid (C/64, R/64)
__global__ __launch_bounds__(256) void tcast_k(const float* __restrict__ W,
                                               uint16_t* __restrict__ Wt,
                                               int R, int C, float scale) {
  __shared__ float T[64][65];
  int c0 = blockIdx.x * 64, r0 = blockIdx.y * 64;
  int tid = threadIdx.x;
  int cc = tid & 63;
  for (int rr = tid >> 6; rr < 64; rr += 4)
    T[rr][cc] = W[(size_t)(r0 + rr) * C + c0 + cc];
  __syncthreads();
  int n = tid >> 2, kb = (tid & 3) * 16;
  uint16_t* orow = Wt + (size_t)(c0 + n) * R + r0 + kb;
#pragma unroll
  for (int j = 0; j < 16; ++j) orow[j] = f2bf(T[kb + j][n] * scale);
}

// ---------------------------------------------------------------------------
// C[m][n] = sum_k A[m][k] * Bt[n][k]; A,Bt bf16 row-major (K-contiguous).
// 128x128 tile, 4 waves (2x2), BK=64, global_load_lds w/ XOR-swizzled source.
// EPI 0: bf16 dense store (ldc=N).  EPI 1: fp32 + bias[n] store.
template <int EPI>
__global__ __launch_bounds__(256) void gemm_bt_k(const uint16_t* __restrict__ A,
                                                 const uint16_t* __restrict__ Bt,
                                                 void* __restrict__ Cv,
                                                 const float* __restrict__ bias,
                                                 int M, int N, int K) {
  __shared__ uint16_t As[128 * 64];
  __shared__ uint16_t Bs[128 * 64];
  const int tid = threadIdx.x;
  const int wv = tid >> 6, lane = tid & 63;
  const int ql = lane & 15, gq = lane >> 4;
  const int wr = wv >> 1, wc = wv & 1;
  const int m0 = blockIdx.y * 128, n0 = blockIdx.x * 128;

  f32x4 acc[4][4];
#pragma unroll
  for (int i = 0; i < 4; ++i)
#pragma unroll
    for (int j = 0; j < 4; ++j) acc[i][j] = (f32x4){0.f, 0.f, 0.f, 0.f};

  const int nkb = K >> 6;
  for (int kb = 0; kb < nkb; ++kb) {
    // stage tiles: slot (row, c) holds global 16B-chunk (c ^ (row&7))
#pragma unroll
    for (int j = 0; j < 4; ++j) {
      int s = (wv * 4 + j) * 64 + lane;
      int row = s >> 3, c = s & 7;
      int gc = c ^ (row & 7);
      gll16(A + (size_t)(m0 + row) * K + kb * 64 + gc * 8, &As[(wv * 4 + j) * 512]);
      gll16(Bt + (size_t)(n0 + row) * K + kb * 64 + gc * 8, &Bs[(wv * 4 + j) * 512]);
    }
    __syncthreads();

    short8 af[4][2], bf[4][2];
#pragma unroll
    for (int mt = 0; mt < 4; ++mt)
#pragma unroll
      for (int kk = 0; kk < 2; ++kk) {
        int row = wr * 64 + mt * 16 + ql;
        int c = (kk * 4 + gq) ^ (row & 7);
        af[mt][kk] = *(const short8*)&As[row * 64 + c * 8];
      }
#pragma unroll
    for (int nt = 0; nt < 4; ++nt)
#pragma unroll
      for (int kk = 0; kk < 2; ++kk) {
        int row = wc * 64 + nt * 16 + ql;
        int c = (kk * 4 + gq) ^ (row & 7);
        bf[nt][kk] = *(const short8*)&Bs[row * 64 + c * 8];
      }
#pragma unroll
    for (int kk = 0; kk < 2; ++kk)
#pragma unroll
      for (int mt = 0; mt < 4; ++mt)
#pragma unroll
        for (int nt = 0; nt < 4; ++nt)
          acc[mt][nt] = MFMA16(af[mt][kk], bf[nt][kk], acc[mt][nt]);
    __syncthreads();
  }

  // epilogue: D layout col=lane&15, row=(lane>>4)*4+r  [m89 verified]
#pragma unroll
  for (int mt = 0; mt < 4; ++mt)
#pragma unroll
    for (int nt = 0; nt < 4; ++nt)
#pragma unroll
      for (int r = 0; r < 4; ++r) {
        int m = m0 + wr * 64 + mt * 16 + gq * 4 + r;
        int n = n0 + wc * 64 + nt * 16 + ql;
        float v = acc[mt][nt][r];
        if (EPI == 0) {
          ((uint16_t*)Cv)[(size_t)m * N + n] = f2bf(v);
        } else {
          ((float*)Cv)[(size_t)m * N + n] = v + bias[n];
        }
      }
}

// ---------------------------------------------------------------------------
// Flash attention. Block = (qb, h, bb): 64 q-rows; 4 waves x 16 rows each.
// q/k dense [nb*2048][2048] bf16 (head slice at col h*256); vt [2048][nb*2048].
// ctx written bf16 to [8192][2048] (global batch rows).
__global__ __launch_bounds__(256) void attn_k(const uint16_t* __restrict__ qws,
                                              const uint16_t* __restrict__ kws,
                                              const uint16_t* __restrict__ vtws,
                                              uint16_t* __restrict__ ctx,
                                              int b0, int nb) {
  __shared__ uint16_t Ks[64 * 256];    // [key][d], chunks XOR (key&15)
  __shared__ uint16_t Vts[256 * 64];   // [d][key], chunks XOR (d&7)
  __shared__ uint16_t Ps[4 * 16 * 72]; // per-wave P tile, row stride 72
  const int S = 2048;
  const int qb = blockIdx.x, h = blockIdx.y, bb = blockIdx.z;
  const int tid = threadIdx.x, wv = tid >> 6, lane = tid & 63;
  const int ql = lane & 15, gq = lane >> 4;
  const size_t SN = (size_t)nb * S;

  // Q fragments in registers: 16 rows x 256 d per wave
  short8 qf[8];
  {
    const uint16_t* qrow = qws + (size_t)(bb * S + qb * 64 + wv * 16 + ql) * 2048 + h * 256;
#pragma unroll
    for (int kk = 0; kk < 8; ++kk) qf[kk] = *(const short8*)(qrow + kk * 32 + gq * 8);
  }

  f32x4 cacc[16];
#pragma unroll
  for (int i = 0; i < 16; ++i) cacc[i] = (f32x4){0.f, 0.f, 0.f, 0.f};
  float mrow[4] = {-1e30f, -1e30f, -1e30f, -1e30f};
  float lrow[4] = {0.f, 0.f, 0.f, 0.f};

  for (int kb = 0; kb < 32; ++kb) {
    // ---- stage K tile (32KB) and Vt tile (32KB)
#pragma unroll
    for (int j = 0; j < 8; ++j) {
      int s = (wv * 8 + j) * 64 + lane;
      int krw = s >> 5, c = s & 31;
      int gc = c ^ (krw & 15);
      gll16(kws + (size_t)(bb * S + kb * 64 + krw) * 2048 + h * 256 + gc * 8,
            &Ks[(wv * 8 + j) * 512]);
      int d = s >> 3, c2 = s & 7;
      int gc2 = c2 ^ (d & 7);
      gll16(vtws + (size_t)(h * 256 + d) * SN + (size_t)bb * S + kb * 64 + gc2 * 8,
            &Vts[(wv * 8 + j) * 512]);
    }
    __syncthreads();

    // ---- S = Q K^T (16 x 64 per wave)
    f32x4 sacc[4];
#pragma unroll
    for (int i = 0; i < 4; ++i) sacc[i] = (f32x4){0.f, 0.f, 0.f, 0.f};
#pragma unroll
    for (int nt = 0; nt < 4; ++nt) {
      int krw = nt * 16 + ql;
#pragma unroll
      for (int kk = 0; kk < 8; ++kk) {
        int c = (kk * 4 + gq) ^ (krw & 15);
        short8 b = *(const short8*)&Ks[krw * 256 + c * 8];
        sacc[nt] = MFMA16(qf[kk], b, sacc[nt]);
      }
    }

    // ---- online softmax (fp32); rows live at (gq*4+r), cols at ql
    float al[4];
#pragma unroll
    for (int r = 0; r < 4; ++r) {
      float mx = fmaxf(fmaxf(sacc[0][r], sacc[1][r]), fmaxf(sacc[2][r], sacc[3][r]));
      mx = fmaxf(mx, __shfl_xor(mx, 1));
      mx = fmaxf(mx, __shfl_xor(mx, 2));
      mx = fmaxf(mx, __shfl_xor(mx, 4));
      mx = fmaxf(mx, __shfl_xor(mx, 8));
      float mn = fmaxf(mrow[r], mx);
      al[r] = __expf(mrow[r] - mn);
      mrow[r] = mn;
      float ps = 0.f;
#pragma unroll
      for (int nt = 0; nt < 4; ++nt) {
        float p = __expf(sacc[nt][r] - mn);
        sacc[nt][r] = p;
        ps += p;
      }
      ps += __shfl_xor(ps, 1); ps += __shfl_xor(ps, 2);
      ps += __shfl_xor(ps, 4); ps += __shfl_xor(ps, 8);
      lrow[r] = lrow[r] * al[r] + ps;
    }

    // ---- P -> LDS (bf16), layout [qrow][key] stride 72
#pragma unroll
    for (int nt = 0; nt < 4; ++nt)
#pragma unroll
      for (int r = 0; r < 4; ++r)
        Ps[wv * 1152 + (gq * 4 + r) * 72 + nt * 16 + ql] = f2bf(sacc[nt][r]);

    // ---- rescale ctx
    {
      f32x4 a4 = {al[0], al[1], al[2], al[3]};
#pragma unroll
      for (int t = 0; t < 16; ++t) cacc[t] *= a4;
    }

    // ---- ctx += P V   (A = P rows(q), B = Vt cols(d))
    short8 pa[2];
#pragma unroll
    for (int k2 = 0; k2 < 2; ++k2)
      pa[k2] = *(const short8*)&Ps[wv * 1152 + ql * 72 + k2 * 32 + gq * 8];
#pragma unroll
    for (int nt = 0; nt < 16; ++nt) {
      int drow = nt * 16 + ql;
#pragma unroll
      for (int k2 = 0; k2 < 2; ++k2) {
        int c = (k2 * 4 + gq) ^ (drow & 7);
        short8 b = *(const short8*)&Vts[drow * 64 + c * 8];
        cacc[nt] = MFMA16(pa[k2], b, cacc[nt]);
      }
    }
    __syncthreads();
  }

  // ---- epilogue: ctx / l -> bf16
  float inv[4];
#pragma unroll
  for (int r = 0; r < 4; ++r) inv[r] = 1.f / lrow[r];
#pragma unroll
  for (int nt = 0; nt < 16; ++nt)
#pragma unroll
    for (int r = 0; r < 4; ++r) {
      int row = gq * 4 + r;
      float v = cacc[nt][r] * inv[r];
      ctx[(size_t)((b0 + bb) * S + qb * 64 + wv * 16 + row) * 2048 + h * 256 + nt * 16 + ql] =
          f2bf(v);
    }
}

// ---------------------------------------------------------------------------
extern "C" void kernel_launch(void* const* d_in, const int* in_sizes, int n_in,
                              void* d_out, int out_size, void* d_ws, size_t ws_size,
                              hipStream_t stream) {
  const float* X  = (const float*)d_in[0];
  const float* Wq = (const float*)d_in[1];
  const float* Wk = (const float*)d_in[2];
  const float* Wv = (const float*)d_in[3];
  const float* Wo = (const float*)d_in[4];
  const float* bo = (const float*)d_in[5];
  float* out = (float*)d_out;

  const int B = 4, S = 2048, Dm = 256, H = 8, DH = 2048;  // DH = H * 256
  (void)in_sizes; (void)n_in; (void)out_size; (void)H;

  uint16_t* p = (uint16_t*)d_ws;
  uint16_t* Xb  = p; p += (size_t)B * S * Dm;   // 2.10M el
  uint16_t* Wqt = p; p += (size_t)DH * Dm;      // 0.52M
  uint16_t* Wkt = p; p += (size_t)DH * Dm;
  uint16_t* Wvt = p; p += (size_t)DH * Dm;
  uint16_t* Wot = p; p += (size_t)Dm * DH;
  uint16_t* ctx = p; p += (size_t)B * S * DH;   // 16.8M
  size_t base_elems = (size_t)(p - (uint16_t*)d_ws);
  size_t per_nb = 3ull * S * DH;                // q,k,vt per batch
  int nb = (ws_size >= (base_elems + 4 * per_nb) * 2) ? 4 : 1;
  uint16_t* qws  = p; p += (size_t)nb * S * DH;
  uint16_t* kws  = p; p += (size_t)nb * S * DH;
  uint16_t* vtws = p;

  // casts
  cast_x_k<<<dim3((B * S * Dm / 4 + 255) / 256), 256, 0, stream>>>(X, Xb, B * S * Dm / 4);
  tcast_k<<<dim3(DH / 64, Dm / 64), 256, 0, stream>>>(Wq, Wqt, Dm, DH, 0.25f);
  tcast_k<<<dim3(DH / 64, Dm / 64), 256, 0, stream>>>(Wk, Wkt, Dm, DH, 0.25f);
  tcast_k<<<dim3(DH / 64, Dm / 64), 256, 0, stream>>>(Wv, Wvt, Dm, DH, 1.0f);
  tcast_k<<<dim3(Dm / 64, DH / 64), 256, 0, stream>>>(Wo, Wot, DH, Dm, 1.0f);

  for (int c = 0; c < B / nb; ++c) {
    const uint16_t* Xc = Xb + (size_t)c * nb * S * Dm;
    int Mq = nb * S;
    // q = Xc @ Wqt^T : [Mq][2048]
    gemm_bt_k<0><<<dim3(DH / 128, Mq / 128), 256, 0, stream>>>(Xc, Wqt, qws, nullptr, Mq, DH, Dm);
    gemm_bt_k<0><<<dim3(DH / 128, Mq / 128), 256, 0, stream>>>(Xc, Wkt, kws, nullptr, Mq, DH, Dm);
    // vt = Wvt @ Xc^T : [2048][Mq]
    gemm_bt_k<0><<<dim3(Mq / 128, DH / 128), 256, 0, stream>>>(Wvt, Xc, vtws, nullptr, DH, Mq, Dm);
    attn_k<<<dim3(S / 64, 8, nb), 256, 0, stream>>>(qws, kws, vtws, ctx, c * nb, nb);
  }
  // out = ctx @ Wot^T + bo : [8192][256] fp32
  gemm_bt_k<1><<<dim3(Dm / 128, (B * S) / 128), 256, 0, stream>>>(ctx, Wot, out, bo, B * S, Dm, DH);
}